// Round 6
// baseline (33.747 us; speedup 1.0000x reference)
//
#include <hip/hip_runtime.h>
#include <stdint.h>

#define B_DIM 64
#define L_DIM 4096
#define D_DIM 256
#define TGT 256
#define BLK 256                      // threads per block (4 waves)
#define ROWS_PER_BLOCK 8
#define NG (TGT / ROWS_PER_BLOCK)    // 32 groups per batch

__device__ __forceinline__ int idx_of(int k, float nf) {
    // matches jnp: minimum(round(k/256 * n), n-1) with round-half-even
    float x = rintf((float)k * (1.0f / 256.0f) * nf);
    x = fminf(x, nf - 1.0f);
    return (int)x;
}

__global__ __launch_bounds__(BLK)
void AggregateVideo_kernel(const uint8_t* __restrict__ mask_raw,
                           const float* __restrict__ feats,
                           float* __restrict__ out) {
    __shared__ unsigned short pos[L_DIM];           // compact idx -> original row
    __shared__ unsigned long long words[L_DIM / 64];
    __shared__ int pref[L_DIM / 64];
    __shared__ int flags[2];
    __shared__ int nsh;

    const int tid  = threadIdx.x;
    const int b    = blockIdx.y;
    const int g    = blockIdx.x;
    const int wv   = tid >> 6;
    const int lane = tid & 63;

    // ---- mask dtype detection on first 4096 bytes (valid under all layouts)
    if (tid == 0) { flags[0] = 1; flags[1] = 1; }
    __syncthreads();
    {
        const uint32_t* mw = (const uint32_t*)mask_raw;
        bool bad_int = false, bad_f32 = false;
        #pragma unroll
        for (int i = 0; i < 4; ++i) {
            uint32_t w = mw[tid + BLK * i];
            if (w > 1u) bad_int = true;
            if (w != 0u && w != 0x3F800000u) bad_f32 = true;
        }
        if (bad_int) flags[0] = 0;
        if (bad_f32) flags[1] = 0;
    }
    __syncthreads();
    const int flag = flags[0] ? 1 : (flags[1] ? 2 : 0); // 1=int32, 2=f32, 0=byte

    // ---- ballot-compaction: coalesced mask loads -> 64 bitmask words
    {
        if (flag == 1) {
            const int32_t* m = (const int32_t*)mask_raw + (size_t)b * L_DIM;
            #pragma unroll
            for (int i = 0; i < L_DIM / BLK; ++i) {
                const int j = i * BLK + tid;
                unsigned long long bal = __ballot(m[j] != 0);
                if (lane == 0) words[j >> 6] = bal;
            }
        } else if (flag == 2) {
            const float* m = (const float*)mask_raw + (size_t)b * L_DIM;
            #pragma unroll
            for (int i = 0; i < L_DIM / BLK; ++i) {
                const int j = i * BLK + tid;
                unsigned long long bal = __ballot(m[j] != 0.0f);
                if (lane == 0) words[j >> 6] = bal;
            }
        } else {
            const uint8_t* m = mask_raw + (size_t)b * L_DIM;
            #pragma unroll
            for (int i = 0; i < L_DIM / BLK; ++i) {
                const int j = i * BLK + tid;
                unsigned long long bal = __ballot(m[j] != 0);
                if (lane == 0) words[j >> 6] = bal;
            }
        }
    }
    __syncthreads();

    // ---- wave 0: popcount + inclusive shfl-scan over the 64 words
    if (tid < 64) {
        const unsigned long long wd = words[tid];
        const int c = __popcll(wd);
        int inc = c;
        #pragma unroll
        for (int off = 1; off < 64; off <<= 1) {
            int v = __shfl_up(inc, off);
            if (tid >= off) inc += v;
        }
        pref[tid] = inc - c;            // exclusive prefix
        if (tid == 63) nsh = inc;       // n
    }
    __syncthreads();

    // ---- expand bitmask words to pos[] (each thread: one 16-bit chunk)
    {
        const int w      = tid >> 2;
        const int startb = (tid & 3) * 16;
        const unsigned long long wd = words[w];
        const unsigned long long below =
            startb ? (wd & ((1ull << startb) - 1ull)) : 0ull;
        int p = pref[w] + __popcll(below);
        const int base = w * 64 + startb;
        unsigned int chunk = (unsigned int)((wd >> startb) & 0xFFFFull);
        while (chunk) {
            const int bit = __ffs(chunk) - 1;
            pos[p++] = (unsigned short)(base + bit);
            chunk &= chunk - 1;
        }
    }
    __syncthreads();

    const float nf = (float)nsh;
    const float* fb = feats + (size_t)b * L_DIM * D_DIM;

    // ---- gather: wave wv owns two CONSECUTIVE buckets (monotone addr stream)
    #pragma unroll
    for (int rr = 0; rr < 2; ++rr) {
        const int t  = g * ROWS_PER_BLOCK + wv * 2 + rr;
        const int s  = idx_of(t, nf);
        const int e  = idx_of(t + 1, nf);
        const int lo = s;
        const int hi = (e > s) ? e : (s + 1);      // s==e -> copy row s
        const float inv = 1.0f / (float)(hi - lo);
        float4 acc = make_float4(0.f, 0.f, 0.f, 0.f);
        for (int i = lo; i < hi; ++i) {
            const int row = pos[i];                // LDS broadcast (conflict-free)
            const float4 v = *((const float4*)(fb + (size_t)row * D_DIM) + lane);
            acc.x += v.x; acc.y += v.y; acc.z += v.z; acc.w += v.w;
        }
        acc.x *= inv; acc.y *= inv; acc.z *= inv; acc.w *= inv;
        *((float4*)(out + ((size_t)b * TGT + t) * D_DIM) + lane) = acc;
    }
}

extern "C" void kernel_launch(void* const* d_in, const int* in_sizes, int n_in,
                              void* d_out, int out_size, void* d_ws, size_t ws_size,
                              hipStream_t stream) {
    const float*   feats = (const float*)d_in[0];
    const uint8_t* masks = (const uint8_t*)d_in[1];
    float*         out   = (float*)d_out;
    (void)in_sizes; (void)n_in; (void)out_size; (void)d_ws; (void)ws_size;

    dim3 grid(NG, B_DIM);
    AggregateVideo_kernel<<<grid, BLK, 0, stream>>>(masks, feats, out);
}

// Round 7
// 33.452 us; speedup vs baseline: 1.0088x; 1.0088x over previous
//
#include <hip/hip_runtime.h>
#include <stdint.h>

#define B_DIM 64
#define L_DIM 4096
#define D_DIM 256
#define TGT 256
#define BLK 256                      // threads per block (4 waves)
#define ROWS_PER_BLOCK 8
#define NG (TGT / ROWS_PER_BLOCK)    // 32 groups per batch

__device__ __forceinline__ int idx_of(int k, float nf) {
    // matches jnp: minimum(round(k/256 * n), n-1) with round-half-even
    float x = rintf((float)k * (1.0f / 256.0f) * nf);
    x = fminf(x, nf - 1.0f);
    return (int)x;
}

__global__ __launch_bounds__(BLK)
void AggregateVideo_kernel(const uint8_t* __restrict__ mask_raw,
                           const float* __restrict__ feats,
                           float* __restrict__ out) {
    __shared__ unsigned short pos[L_DIM];           // compact idx -> original row
    __shared__ unsigned long long words[L_DIM / 64];
    __shared__ int pref[L_DIM / 64];
    __shared__ int flags[2];
    __shared__ int nsh;

    const int tid  = threadIdx.x;
    const int b    = blockIdx.y;
    const int g    = blockIdx.x;
    const int wv   = tid >> 6;
    const int lane = tid & 63;

    // ---- mask dtype detection on first 4096 bytes (valid under all layouts)
    if (tid == 0) { flags[0] = 1; flags[1] = 1; }
    __syncthreads();
    {
        const uint32_t* mw = (const uint32_t*)mask_raw;
        bool bad_int = false, bad_f32 = false;
        #pragma unroll
        for (int i = 0; i < 4; ++i) {
            uint32_t w = mw[tid + BLK * i];
            if (w > 1u) bad_int = true;
            if (w != 0u && w != 0x3F800000u) bad_f32 = true;
        }
        if (bad_int) flags[0] = 0;
        if (bad_f32) flags[1] = 0;
    }
    __syncthreads();
    const int flag = flags[0] ? 1 : (flags[1] ? 2 : 0); // 1=int32, 2=f32, 0=byte

    // ---- ballot-compaction: coalesced mask loads -> 64 bitmask words
    {
        if (flag == 1) {
            const int32_t* m = (const int32_t*)mask_raw + (size_t)b * L_DIM;
            #pragma unroll
            for (int i = 0; i < L_DIM / BLK; ++i) {
                const int j = i * BLK + tid;
                unsigned long long bal = __ballot(m[j] != 0);
                if (lane == 0) words[j >> 6] = bal;
            }
        } else if (flag == 2) {
            const float* m = (const float*)mask_raw + (size_t)b * L_DIM;
            #pragma unroll
            for (int i = 0; i < L_DIM / BLK; ++i) {
                const int j = i * BLK + tid;
                unsigned long long bal = __ballot(m[j] != 0.0f);
                if (lane == 0) words[j >> 6] = bal;
            }
        } else {
            const uint8_t* m = mask_raw + (size_t)b * L_DIM;
            #pragma unroll
            for (int i = 0; i < L_DIM / BLK; ++i) {
                const int j = i * BLK + tid;
                unsigned long long bal = __ballot(m[j] != 0);
                if (lane == 0) words[j >> 6] = bal;
            }
        }
    }
    __syncthreads();

    // ---- wave 0: popcount + inclusive shfl-scan over the 64 words
    if (tid < 64) {
        const unsigned long long wd = words[tid];
        const int c = __popcll(wd);
        int inc = c;
        #pragma unroll
        for (int off = 1; off < 64; off <<= 1) {
            int v = __shfl_up(inc, off);
            if (tid >= off) inc += v;
        }
        pref[tid] = inc - c;            // exclusive prefix
        if (tid == 63) nsh = inc;       // n
    }
    __syncthreads();

    // ---- expand bitmask words to pos[] (each thread: one 16-bit chunk)
    {
        const int w      = tid >> 2;
        const int startb = (tid & 3) * 16;
        const unsigned long long wd = words[w];
        const unsigned long long below =
            startb ? (wd & ((1ull << startb) - 1ull)) : 0ull;
        int p = pref[w] + __popcll(below);
        const int base = w * 64 + startb;
        unsigned int chunk = (unsigned int)((wd >> startb) & 0xFFFFull);
        while (chunk) {
            const int bit = __ffs(chunk) - 1;
            pos[p++] = (unsigned short)(base + bit);
            chunk &= chunk - 1;
        }
    }
    __syncthreads();

    const float nf = (float)nsh;

    // ---- gather: EXACT R1 structure — wave wv takes buckets wv and wv+4
    for (int r = wv; r < ROWS_PER_BLOCK; r += 4) {
        const int t = g * ROWS_PER_BLOCK + r;
        const int s = idx_of(t, nf);
        const int e = idx_of(t + 1, nf);
        const int lo = s;
        const int hi = (e > s) ? e : (s + 1);   // s==e -> single-row copy
        const float inv = 1.0f / (float)(hi - lo);
        float4 acc = make_float4(0.f, 0.f, 0.f, 0.f);
        for (int i = lo; i < hi; ++i) {
            const int row = pos[i];             // LDS broadcast (conflict-free)
            const float4 v =
                *((const float4*)(feats + ((size_t)b * L_DIM + row) * D_DIM) + lane);
            acc.x += v.x; acc.y += v.y; acc.z += v.z; acc.w += v.w;
        }
        acc.x *= inv; acc.y *= inv; acc.z *= inv; acc.w *= inv;
        *((float4*)(out + ((size_t)b * TGT + t) * D_DIM) + lane) = acc;
    }
}

extern "C" void kernel_launch(void* const* d_in, const int* in_sizes, int n_in,
                              void* d_out, int out_size, void* d_ws, size_t ws_size,
                              hipStream_t stream) {
    const float*   feats = (const float*)d_in[0];
    const uint8_t* masks = (const uint8_t*)d_in[1];
    float*         out   = (float*)d_out;
    (void)in_sizes; (void)n_in; (void)out_size; (void)d_ws; (void)ws_size;

    dim3 grid(NG, B_DIM);
    AggregateVideo_kernel<<<grid, BLK, 0, stream>>>(masks, feats, out);
}

// Round 8
// 30.672 us; speedup vs baseline: 1.1002x; 1.0906x over previous
//
#include <hip/hip_runtime.h>
#include <stdint.h>

#define B_DIM 64
#define L_DIM 4096
#define D_DIM 256
#define TGT 256
#define NG 32                        // row-groups per batch
#define ROWS_PER_BLOCK (TGT / NG)    // 8

__device__ __forceinline__ int idx_of(int k, float nf) {
    // matches jnp: minimum(round(k/256 * n), n-1) with round-half-even
    float x = rintf((float)k * (1.0f / 256.0f) * nf);
    x = fminf(x, nf - 1.0f);
    return (int)x;
}

__global__ __launch_bounds__(256)
void AggregateVideo_kernel(const uint8_t* __restrict__ mask_raw,
                           const float* __restrict__ feats,
                           float* __restrict__ out) {
    __shared__ unsigned short pos[L_DIM];  // compacted-row -> original row
    __shared__ int tsum[256];
    __shared__ int flags[2];

    const int tid = threadIdx.x;
    const int b   = blockIdx.y;
    const int g   = blockIdx.x;

    // ---- mask dtype detection on first 4096 bytes (safe under all layouts)
    if (tid == 0) { flags[0] = 1; flags[1] = 1; }
    __syncthreads();
    {
        const uint32_t* mw = (const uint32_t*)mask_raw;
        bool bad_int = false, bad_f32 = false;
        #pragma unroll
        for (int i = 0; i < 4; ++i) {
            uint32_t w = mw[tid + 256 * i];
            if (w > 1u) bad_int = true;
            if (w != 0u && w != 0x3F800000u) bad_f32 = true;
        }
        if (bad_int) flags[0] = 0;
        if (bad_f32) flags[1] = 0;
    }
    __syncthreads();
    const int flag = flags[0] ? 1 : (flags[1] ? 2 : 0); // 1=int32, 2=f32, 0=byte

    // ---- load this batch's mask; block scan -> pos[], n
    uint32_t bits = 0;
    int cnt = 0;
    {
        const int base = tid * 16;
        if (flag == 1) {
            const int32_t* m = (const int32_t*)mask_raw + (size_t)b * L_DIM;
            #pragma unroll
            for (int i = 0; i < 16; ++i)
                if (m[base + i] != 0) { bits |= (1u << i); ++cnt; }
        } else if (flag == 2) {
            const float* m = (const float*)mask_raw + (size_t)b * L_DIM;
            #pragma unroll
            for (int i = 0; i < 16; ++i)
                if (m[base + i] != 0.0f) { bits |= (1u << i); ++cnt; }
        } else {
            const uint8_t* m = mask_raw + (size_t)b * L_DIM;
            #pragma unroll
            for (int i = 0; i < 16; ++i)
                if (m[base + i] != 0) { bits |= (1u << i); ++cnt; }
        }
    }
    tsum[tid] = cnt;
    __syncthreads();
    // Hillis-Steele inclusive scan over 256 per-thread counts
    for (int off = 1; off < 256; off <<= 1) {
        int v = (tid >= off) ? tsum[tid - off] : 0;
        __syncthreads();
        tsum[tid] += v;
        __syncthreads();
    }
    const int n = tsum[255];
    {
        int p = tsum[tid] - cnt;           // exclusive prefix
        const int base = tid * 16;
        #pragma unroll
        for (int i = 0; i < 16; ++i)
            if ((bits >> i) & 1u) pos[p++] = (unsigned short)(base + i);
    }
    __syncthreads();

    const float nf = (float)n;

    // ---- compute 8 output rows for this (batch, group)
    const int wv   = tid >> 6;   // wave id 0..3
    const int lane = tid & 63;
    for (int r = wv; r < ROWS_PER_BLOCK; r += 4) {
        const int t = g * ROWS_PER_BLOCK + r;
        const int s = idx_of(t, nf);
        const int e = idx_of(t + 1, nf);
        const int lo = s;
        const int hi = (e > s) ? e : (s + 1);   // s==e -> single-row copy
        const float inv = 1.0f / (float)(hi - lo);
        float4 acc = make_float4(0.f, 0.f, 0.f, 0.f);
        for (int i = lo; i < hi; ++i) {
            const int row = pos[i];             // LDS broadcast (conflict-free)
            const float4 v =
                *((const float4*)(feats + ((size_t)b * L_DIM + row) * D_DIM) + lane);
            acc.x += v.x; acc.y += v.y; acc.z += v.z; acc.w += v.w;
        }
        acc.x *= inv; acc.y *= inv; acc.z *= inv; acc.w *= inv;
        *((float4*)(out + ((size_t)b * TGT + t) * D_DIM) + lane) = acc;
    }
}

extern "C" void kernel_launch(void* const* d_in, const int* in_sizes, int n_in,
                              void* d_out, int out_size, void* d_ws, size_t ws_size,
                              hipStream_t stream) {
    const float*   feats = (const float*)d_in[0];
    const uint8_t* masks = (const uint8_t*)d_in[1];
    float*         out   = (float*)d_out;
    (void)in_sizes; (void)n_in; (void)out_size; (void)d_ws; (void)ws_size;

    dim3 grid(NG, B_DIM);
    AggregateVideo_kernel<<<grid, 256, 0, stream>>>(masks, feats, out);
}